// Round 2
// baseline (225.375 us; speedup 1.0000x reference)
//
#include <hip/hip_runtime.h>
#include <hip/hip_bf16.h>

// Problem constants: B=8, S=1024, D=1024, H=16, DH=64, N=H*DH=1024, M=B*S=8192
// ws layout (bf16): q[8M] | k[8M] | vt[8M] | wt_q[1M] | wt_k[1M] | wt_v[1M]  = 54 MB

typedef __bf16 bf16;
typedef float f32x4 __attribute__((ext_vector_type(4)));
typedef bf16 bf16x8 __attribute__((ext_vector_type(8)));

#define LOG2E 1.4426950408889634f

static __device__ __forceinline__ f32x4 mfma16(bf16x8 a, bf16x8 b, f32x4 c) {
    return __builtin_amdgcn_mfma_f32_16x16x32_bf16(a, b, c, 0, 0, 0);
}

// ---------------- weight transpose + convert: W[k][n] f32 -> Wt[n][k] bf16 ----
__global__ __launch_bounds__(256)
void wconv_kernel(const float* __restrict__ W, bf16* __restrict__ Wt) {
    __shared__ bf16 t[32][33];
    const int tx = threadIdx.x, ty = threadIdx.y;
    const int n0 = blockIdx.x * 32, k0 = blockIdx.y * 32;
#pragma unroll
    for (int i = 0; i < 4; ++i)
        t[ty + i * 8][tx] = (bf16)W[(size_t)(k0 + ty + i * 8) * 1024 + n0 + tx];
    __syncthreads();
#pragma unroll
    for (int i = 0; i < 4; ++i)
        Wt[(size_t)(n0 + ty + i * 8) * 1024 + k0 + tx] = t[tx][ty + i * 8];
}

// ---------------- projection GEMM: C[8192,1024] = X(f32) @ W, bf16 MFMA -------
// MODE 0: out[((b*16+h)*1024+s)*64+dh]   (Q/K layout [bh][s][dh])
// MODE 1: out[((b*16+h)*64+dh)*1024+s]   (V transposed  [bh][dh][s])
template <int MODE>
__global__ __launch_bounds__(256)
void gemm_proj(const float* __restrict__ X, const bf16* __restrict__ Wt,
               bf16* __restrict__ out) {
    __shared__ bf16 Asub[128][40];   // +8 pad: row stride 80B -> conflict-free b128
    __shared__ bf16 Bsub[128][40];
    const int tid = threadIdx.x;
    const int lane = tid & 63;
    const int w = tid >> 6;
    const int m0 = blockIdx.x * 128;
    const int n0 = blockIdx.y * 128;
    const int wm = (w >> 1) * 64;
    const int wn = (w & 1) * 64;
    const int lrow = lane & 15;
    const int lk8 = (lane >> 4) * 8;
    const int lr4 = (lane >> 4) * 4;

    f32x4 acc[4][4];
#pragma unroll
    for (int i = 0; i < 4; ++i)
#pragma unroll
        for (int j = 0; j < 4; ++j)
            acc[i][j] = f32x4{0.f, 0.f, 0.f, 0.f};

    const int srow = tid >> 1;
    const int skh = (tid & 1) * 16;
    const float* xg = X + (size_t)(m0 + srow) * 1024 + skh;
    const bf16* bg = Wt + (size_t)(n0 + srow) * 1024 + skh;

    for (int kt = 0; kt < 32; ++kt) {
        const int k0 = kt * 32;
        const float4 f0 = *(const float4*)(xg + k0 + 0);
        const float4 f1 = *(const float4*)(xg + k0 + 4);
        const float4 f2 = *(const float4*)(xg + k0 + 8);
        const float4 f3 = *(const float4*)(xg + k0 + 12);
        const bf16x8 b0 = *(const bf16x8*)(bg + k0 + 0);
        const bf16x8 b1 = *(const bf16x8*)(bg + k0 + 8);
        bf16x8 a0, a1;
        a0[0] = (bf16)f0.x; a0[1] = (bf16)f0.y; a0[2] = (bf16)f0.z; a0[3] = (bf16)f0.w;
        a0[4] = (bf16)f1.x; a0[5] = (bf16)f1.y; a0[6] = (bf16)f1.z; a0[7] = (bf16)f1.w;
        a1[0] = (bf16)f2.x; a1[1] = (bf16)f2.y; a1[2] = (bf16)f2.z; a1[3] = (bf16)f2.w;
        a1[4] = (bf16)f3.x; a1[5] = (bf16)f3.y; a1[6] = (bf16)f3.z; a1[7] = (bf16)f3.w;
        __syncthreads();  // previous tile's compute done
        *(bf16x8*)&Asub[srow][skh + 0] = a0;
        *(bf16x8*)&Asub[srow][skh + 8] = a1;
        *(bf16x8*)&Bsub[srow][skh + 0] = b0;
        *(bf16x8*)&Bsub[srow][skh + 8] = b1;
        __syncthreads();  // tile ready
        bf16x8 af[4], bfv[4];
#pragma unroll
        for (int i = 0; i < 4; ++i)
            af[i] = *(const bf16x8*)&Asub[wm + i * 16 + lrow][lk8];
#pragma unroll
        for (int j = 0; j < 4; ++j)
            bfv[j] = *(const bf16x8*)&Bsub[wn + j * 16 + lrow][lk8];
#pragma unroll
        for (int i = 0; i < 4; ++i)
#pragma unroll
            for (int j = 0; j < 4; ++j)
                acc[i][j] = mfma16(af[i], bfv[j], acc[i][j]);
    }

    // epilogue: C/D layout col=lane&15, row=(lane>>4)*4+reg  [m89-verified]
#pragma unroll
    for (int j = 0; j < 4; ++j) {
        const int n = n0 + wn + j * 16 + lrow;
        const int h = n >> 6, dh = n & 63;
#pragma unroll
        for (int i = 0; i < 4; ++i) {
#pragma unroll
            for (int r = 0; r < 4; ++r) {
                const int m = m0 + wm + i * 16 + lr4 + r;
                const int b = m >> 10, s = m & 1023;
                const bf16 val = (bf16)acc[i][j][r];
                if (MODE == 0)
                    out[((size_t)((b * 16 + h) * 1024 + s)) * 64 + dh] = val;
                else
                    out[((size_t)((b * 16 + h) * 64 + dh)) * 1024 + s] = val;
            }
        }
    }
}

// ---------------- flash attention: 1 block = (bh, 64 q rows), 4 waves --------
__global__ __launch_bounds__(256)
void attn_kernel(const bf16* __restrict__ Q, const bf16* __restrict__ K,
                 const bf16* __restrict__ Vt, float* __restrict__ out) {
    __shared__ bf16 Ksub[128][72];    // KBLK=128 keys x 64 dh, +8 pad
    __shared__ bf16 Vsub[64][136];    // 64 dh x KBLK keys (V^T), +8 pad
    __shared__ bf16 Psub[4][16][136]; // per-wave P tile 16 q x 128 keys, +8 pad

    const int tid = threadIdx.x, lane = tid & 63, w = tid >> 6;
    // XCD-aware decode: all 16 q-tiles of one bh land on one XCD (lin%8 const)
    const int lin = blockIdx.x;          // 0..2047
    const int xcd = lin & 7;
    const int slot = lin >> 3;           // 0..255
    const int bh = (slot >> 4) * 8 + xcd;  // 0..127
    const int qt = slot & 15;
    const int q0 = qt * 64;

    const size_t base = (size_t)bh << 16;  // bh * 1024 * 64
    const int lrow = lane & 15, lk8 = (lane >> 4) * 8, lr4 = (lane >> 4) * 4;

    // Q fragments (16 rows per wave), hoisted
    const bf16* qg = Q + base + (size_t)(q0 + w * 16 + lrow) * 64 + lk8;
    const bf16x8 qf0 = *(const bf16x8*)qg;
    const bf16x8 qf1 = *(const bf16x8*)(qg + 32);

    f32x4 o[4];
#pragma unroll
    for (int n = 0; n < 4; ++n) o[n] = f32x4{0.f, 0.f, 0.f, 0.f};
    float m_r[4], l_r[4];
#pragma unroll
    for (int r = 0; r < 4; ++r) { m_r[r] = -__builtin_inff(); l_r[r] = 0.f; }

    const bf16* kg = K + base + (size_t)(tid >> 1) * 64 + (tid & 1) * 32;
    const bf16* vg = Vt + base + (size_t)(tid >> 2) * 1024 + (tid & 3) * 32;
    bf16* kdst = &Ksub[tid >> 1][(tid & 1) * 32];
    bf16* vdst = &Vsub[tid >> 2][(tid & 3) * 32];

    for (int t = 0; t < 8; ++t) {
        const int s0 = t * 128;
        const bf16x8 kv0 = *(const bf16x8*)(kg + s0 * 64 + 0);
        const bf16x8 kv1 = *(const bf16x8*)(kg + s0 * 64 + 8);
        const bf16x8 kv2 = *(const bf16x8*)(kg + s0 * 64 + 16);
        const bf16x8 kv3 = *(const bf16x8*)(kg + s0 * 64 + 24);
        const bf16x8 vv0 = *(const bf16x8*)(vg + s0 + 0);
        const bf16x8 vv1 = *(const bf16x8*)(vg + s0 + 8);
        const bf16x8 vv2 = *(const bf16x8*)(vg + s0 + 16);
        const bf16x8 vv3 = *(const bf16x8*)(vg + s0 + 24);
        __syncthreads();
        *(bf16x8*)(kdst + 0) = kv0; *(bf16x8*)(kdst + 8) = kv1;
        *(bf16x8*)(kdst + 16) = kv2; *(bf16x8*)(kdst + 24) = kv3;
        *(bf16x8*)(vdst + 0) = vv0; *(bf16x8*)(vdst + 8) = vv1;
        *(bf16x8*)(vdst + 16) = vv2; *(bf16x8*)(vdst + 24) = vv3;
        __syncthreads();

        // QK^T: 16 q rows x 128 keys (8 n-frags x 2 k-steps)
        f32x4 sf[8];
#pragma unroll
        for (int j = 0; j < 8; ++j) {
            const bf16x8 kf0 = *(const bf16x8*)&Ksub[j * 16 + lrow][lk8];
            const bf16x8 kf1 = *(const bf16x8*)&Ksub[j * 16 + lrow][32 + lk8];
            f32x4 z = f32x4{0.f, 0.f, 0.f, 0.f};
            z = mfma16(qf0, kf0, z);
            sf[j] = mfma16(qf1, kf1, z);
        }
        // scale + online softmax (per lane: reg r -> q row lr4+r; lanes 0-15 -> keys)
        float tmax[4];
#pragma unroll
        for (int r = 0; r < 4; ++r) tmax[r] = -__builtin_inff();
#pragma unroll
        for (int j = 0; j < 8; ++j)
#pragma unroll
            for (int r = 0; r < 4; ++r) {
                sf[j][r] *= 0.125f;
                tmax[r] = fmaxf(tmax[r], sf[j][r]);
            }
#pragma unroll
        for (int r = 0; r < 4; ++r) {
            tmax[r] = fmaxf(tmax[r], __shfl_xor(tmax[r], 1));
            tmax[r] = fmaxf(tmax[r], __shfl_xor(tmax[r], 2));
            tmax[r] = fmaxf(tmax[r], __shfl_xor(tmax[r], 4));
            tmax[r] = fmaxf(tmax[r], __shfl_xor(tmax[r], 8));
        }
        float alpha[4];
#pragma unroll
        for (int r = 0; r < 4; ++r) {
            const float mn = fmaxf(m_r[r], tmax[r]);
            alpha[r] = __builtin_amdgcn_exp2f((m_r[r] - mn) * LOG2E);
            m_r[r] = mn;
        }
        float tsum[4] = {0.f, 0.f, 0.f, 0.f};
#pragma unroll
        for (int j = 0; j < 8; ++j)
#pragma unroll
            for (int r = 0; r < 4; ++r) {
                const float p = __builtin_amdgcn_exp2f((sf[j][r] - m_r[r]) * LOG2E);
                sf[j][r] = p;
                tsum[r] += p;
            }
#pragma unroll
        for (int r = 0; r < 4; ++r) {
            tsum[r] += __shfl_xor(tsum[r], 1);
            tsum[r] += __shfl_xor(tsum[r], 2);
            tsum[r] += __shfl_xor(tsum[r], 4);
            tsum[r] += __shfl_xor(tsum[r], 8);
            l_r[r] = l_r[r] * alpha[r] + tsum[r];
        }
#pragma unroll
        for (int n = 0; n < 4; ++n)
#pragma unroll
            for (int r = 0; r < 4; ++r) o[n][r] *= alpha[r];

        // P (C/D layout) -> LDS (per-wave, no barrier needed)
#pragma unroll
        for (int j = 0; j < 8; ++j)
#pragma unroll
            for (int r = 0; r < 4; ++r)
                Psub[w][lr4 + r][j * 16 + lrow] = (bf16)sf[j][r];

        // PV: O[16 q x 64 dh] += P[16 x 128] @ V[128 x 64] (via V^T rows)
#pragma unroll
        for (int kk = 0; kk < 4; ++kk) {
            const bf16x8 pa = *(const bf16x8*)&Psub[w][lrow][kk * 32 + lk8];
#pragma unroll
            for (int n = 0; n < 4; ++n) {
                const bf16x8 vf = *(const bf16x8*)&Vsub[n * 16 + lrow][kk * 32 + lk8];
                o[n] = mfma16(pa, vf, o[n]);
            }
        }
    }

    const int b = bh >> 4, h = bh & 15;
    float inv[4];
#pragma unroll
    for (int r = 0; r < 4; ++r) inv[r] = 1.0f / l_r[r];
#pragma unroll
    for (int n = 0; n < 4; ++n)
#pragma unroll
        for (int r = 0; r < 4; ++r) {
            const int qrow = q0 + w * 16 + lr4 + r;
            out[((size_t)(b * 1024 + qrow)) * 1024 + h * 64 + n * 16 + lrow] =
                o[n][r] * inv[r];
        }
}

extern "C" void kernel_launch(void* const* d_in, const int* in_sizes, int n_in,
                              void* d_out, int out_size, void* d_ws, size_t ws_size,
                              hipStream_t stream) {
    (void)in_sizes; (void)n_in; (void)out_size; (void)ws_size;
    const float* queries = (const float*)d_in[0];
    const float* keys    = (const float*)d_in[1];
    const float* values  = (const float*)d_in[2];
    const float* Wq      = (const float*)d_in[3];
    const float* Wk      = (const float*)d_in[4];
    const float* Wv      = (const float*)d_in[5];
    float* out = (float*)d_out;

    bf16* q_ws  = (bf16*)d_ws;
    bf16* k_ws  = q_ws + (size_t)8 * 1024 * 1024;
    bf16* vt_ws = k_ws + (size_t)8 * 1024 * 1024;
    bf16* wt_q  = vt_ws + (size_t)8 * 1024 * 1024;
    bf16* wt_k  = wt_q + (size_t)1024 * 1024;
    bf16* wt_v  = wt_k + (size_t)1024 * 1024;

    const dim3 wb(32, 8);
    wconv_kernel<<<dim3(32, 32), wb, 0, stream>>>(Wq, wt_q);
    wconv_kernel<<<dim3(32, 32), wb, 0, stream>>>(Wk, wt_k);
    wconv_kernel<<<dim3(32, 32), wb, 0, stream>>>(Wv, wt_v);

    gemm_proj<0><<<dim3(64, 8), 256, 0, stream>>>(queries, wt_q, q_ws);
    gemm_proj<0><<<dim3(64, 8), 256, 0, stream>>>(keys,    wt_k, k_ws);
    gemm_proj<1><<<dim3(64, 8), 256, 0, stream>>>(values,  wt_v, vt_ws);

    attn_kernel<<<dim3(2048), 256, 0, stream>>>(q_ws, k_ws, vt_ws, out);
}

// Round 3
// 222.859 us; speedup vs baseline: 1.0113x; 1.0113x over previous
//
#include <hip/hip_runtime.h>
#include <hip/hip_bf16.h>

// B=8, S=1024, D=1024, H=16, DH=64, N=1024, M=8192
// ws (bf16): q[8M] | k[8M] | vt[8M] | wt_q[1M] | wt_k[1M] | wt_v[1M]

typedef __bf16 bf16;
typedef float f32x4 __attribute__((ext_vector_type(4)));
typedef bf16 bf16x8 __attribute__((ext_vector_type(8)));

#define QK_SCALE 0.18033688011112042f  // 0.125 * log2(e): softmax in base-2 domain

static __device__ __forceinline__ f32x4 mfma16(bf16x8 a, bf16x8 b, f32x4 c) {
    return __builtin_amdgcn_mfma_f32_16x16x32_bf16(a, b, c, 0, 0, 0);
}

#define GLDS16(g, l)                                            \
    __builtin_amdgcn_global_load_lds(                           \
        (const __attribute__((address_space(1))) void*)(g),     \
        (__attribute__((address_space(3))) void*)(l), 16, 0, 0)

// ---------------- weight transpose+convert: W[k][n] f32 -> Wt[n][k] bf16 -----
__global__ __launch_bounds__(256)
void wconv_kernel(const float* __restrict__ Wq, const float* __restrict__ Wk,
                  const float* __restrict__ Wv, bf16* __restrict__ Tq,
                  bf16* __restrict__ Tk, bf16* __restrict__ Tv) {
    const int z = blockIdx.z;
    const float* W = z == 0 ? Wq : (z == 1 ? Wk : Wv);
    bf16* Wt = z == 0 ? Tq : (z == 1 ? Tk : Tv);
    __shared__ bf16 t[32][33];
    const int tx = threadIdx.x, ty = threadIdx.y;
    const int n0 = blockIdx.x * 32, k0 = blockIdx.y * 32;
#pragma unroll
    for (int i = 0; i < 4; ++i)
        t[ty + i * 8][tx] = (bf16)W[(size_t)(k0 + ty + i * 8) * 1024 + n0 + tx];
    __syncthreads();
#pragma unroll
    for (int i = 0; i < 4; ++i)
        Wt[(size_t)(n0 + ty + i * 8) * 1024 + k0 + tx] = t[tx][ty + i * 8];
}

// ---------------- projection GEMM (z=0:Q, z=1:K, z=2:V^T) --------------------
__global__ __launch_bounds__(256)
void gemm_proj(const float* __restrict__ Xq, const float* __restrict__ Xk,
               const float* __restrict__ Xv, const bf16* __restrict__ Tq,
               const bf16* __restrict__ Tk, const bf16* __restrict__ Tv,
               bf16* __restrict__ Oq, bf16* __restrict__ Ok,
               bf16* __restrict__ Ov) {
    __shared__ bf16 Asub[128][40];   // reg-staged fp32->bf16, +8 pad
    __shared__ bf16 Bsub[128][32];   // linear: global_load_lds dest
    const int z = blockIdx.z;
    const float* X = z == 0 ? Xq : (z == 1 ? Xk : Xv);
    const bf16* Wt = z == 0 ? Tq : (z == 1 ? Tk : Tv);
    bf16* out = z == 0 ? Oq : (z == 1 ? Ok : Ov);
    const float oscale = z == 0 ? QK_SCALE : 1.0f;

    const int tid = threadIdx.x;
    const int lane = tid & 63;
    const int w = tid >> 6;
    const int m0 = blockIdx.x * 128;
    const int n0 = blockIdx.y * 128;
    const int wm = (w >> 1) * 64;
    const int wn = (w & 1) * 64;
    const int lrow = lane & 15;
    const int lk8 = (lane >> 4) * 8;
    const int lr4 = (lane >> 4) * 4;

    f32x4 acc[4][4];
#pragma unroll
    for (int i = 0; i < 4; ++i)
#pragma unroll
        for (int j = 0; j < 4; ++j)
            acc[i][j] = f32x4{0.f, 0.f, 0.f, 0.f};

    const int srow = tid >> 1;
    const int skh = (tid & 1) * 16;
    const float* xg = X + (size_t)(m0 + srow) * 1024 + skh;

    for (int kt = 0; kt < 32; ++kt) {
        const int k0 = kt * 32;
        // A: fp32 global -> regs -> bf16 (issued before barrier, overlaps prev MFMA)
        const float4 f0 = *(const float4*)(xg + k0 + 0);
        const float4 f1 = *(const float4*)(xg + k0 + 4);
        const float4 f2 = *(const float4*)(xg + k0 + 8);
        const float4 f3 = *(const float4*)(xg + k0 + 12);
        bf16x8 a0, a1;
        a0[0] = (bf16)f0.x; a0[1] = (bf16)f0.y; a0[2] = (bf16)f0.z; a0[3] = (bf16)f0.w;
        a0[4] = (bf16)f1.x; a0[5] = (bf16)f1.y; a0[6] = (bf16)f1.z; a0[7] = (bf16)f1.w;
        a1[0] = (bf16)f2.x; a1[1] = (bf16)f2.y; a1[2] = (bf16)f2.z; a1[3] = (bf16)f2.w;
        a1[4] = (bf16)f3.x; a1[5] = (bf16)f3.y; a1[6] = (bf16)f3.z; a1[7] = (bf16)f3.w;
        __syncthreads();  // prev tile's LDS reads done
        *(bf16x8*)&Asub[srow][skh + 0] = a0;
        *(bf16x8*)&Asub[srow][skh + 8] = a1;
        // B: async global->LDS, 16B/lane, linear dest (wave-uniform base + lane*16)
#pragma unroll
        for (int c = 0; c < 2; ++c) {
            const int idx = c * 256 + tid;
            const bf16* gsrc = Wt + (size_t)(n0 + (idx >> 2)) * 1024 + k0 + (idx & 3) * 8;
            bf16* ldst = &Bsub[0][0] + (size_t)(c * 256 + w * 64) * 8;
            GLDS16(gsrc, ldst);
        }
        __syncthreads();  // drains vmcnt(0): A written, B landed
        bf16x8 af[4], bfv[4];
#pragma unroll
        for (int i = 0; i < 4; ++i)
            af[i] = *(const bf16x8*)&Asub[wm + i * 16 + lrow][lk8];
#pragma unroll
        for (int j = 0; j < 4; ++j)
            bfv[j] = *(const bf16x8*)&Bsub[wn + j * 16 + lrow][lk8];
        __builtin_amdgcn_s_setprio(1);
#pragma unroll
        for (int i = 0; i < 4; ++i)
#pragma unroll
            for (int j = 0; j < 4; ++j)
                acc[i][j] = mfma16(af[i], bfv[j], acc[i][j]);
        __builtin_amdgcn_s_setprio(0);
    }

    // epilogue: C/D layout col=lane&15, row=(lane>>4)*4+reg  [m89-verified]
#pragma unroll
    for (int j = 0; j < 4; ++j) {
        const int n = n0 + wn + j * 16 + lrow;
        const int h = n >> 6, dh = n & 63;
#pragma unroll
        for (int i = 0; i < 4; ++i) {
#pragma unroll
            for (int r = 0; r < 4; ++r) {
                const int m = m0 + wm + i * 16 + lr4 + r;
                const int b = m >> 10, s = m & 1023;
                const bf16 val = (bf16)(acc[i][j][r] * oscale);
                if (z < 2)
                    out[((size_t)((b * 16 + h) * 1024 + s)) * 64 + dh] = val;
                else
                    out[((size_t)((b * 16 + h) * 64 + dh)) * 1024 + s] = val;
            }
        }
    }
}

// ---------------- flash attention: 1 block = (bh, 128 q rows), 4 waves -------
// Each wave: 32 q rows (2x 16-row fragments). K staged in LDS; V^T read direct
// from global (L2-resident per-XCD via swizzle); P via per-wave LDS tile.
// Q pre-scaled by 0.125*log2e at projection -> softmax in exp2 domain.
__global__ __launch_bounds__(256)
void attn_kernel(const bf16* __restrict__ Q, const bf16* __restrict__ K,
                 const bf16* __restrict__ Vt, float* __restrict__ out) {
    __shared__ bf16 Ksub[128][72];    // 128 keys x 64 dh, +8 pad (18.4 KB)
    __shared__ bf16 Psub[4][32][136]; // per-wave P: 32 q x 128 keys, +8 pad (34.8 KB)

    const int tid = threadIdx.x, lane = tid & 63, w = tid >> 6;
    // XCD decode: all 8 q-tiles of one bh on one XCD (lin&7 = const per bh)
    const int lin = blockIdx.x;           // 0..1023
    const int xcd = lin & 7;
    const int slot = lin >> 3;            // 0..127
    const int bh = (slot >> 3) * 8 + xcd; // 0..127
    const int qt = slot & 7;
    const int q0 = qt * 128;

    const size_t base = (size_t)bh << 16;  // bh * 1024 * 64
    const int lrow = lane & 15, lk8 = (lane >> 4) * 8, lr4 = (lane >> 4) * 4;

    bf16x8 qf[2][2];
#pragma unroll
    for (int h = 0; h < 2; ++h) {
        const bf16* qg = Q + base + (size_t)(q0 + w * 32 + h * 16 + lrow) * 64 + lk8;
        qf[h][0] = *(const bf16x8*)qg;
        qf[h][1] = *(const bf16x8*)(qg + 32);
    }

    f32x4 o[2][4];
    float m_r[2][4], l_r[2][4];
#pragma unroll
    for (int h = 0; h < 2; ++h)
#pragma unroll
        for (int n = 0; n < 4; ++n) o[h][n] = f32x4{0.f, 0.f, 0.f, 0.f};
#pragma unroll
    for (int h = 0; h < 2; ++h)
#pragma unroll
        for (int r = 0; r < 4; ++r) { m_r[h][r] = -__builtin_inff(); l_r[h][r] = 0.f; }

    const bf16* kg = K + base + (size_t)(tid >> 1) * 64 + (tid & 1) * 32;
    bf16* kdst = &Ksub[tid >> 1][(tid & 1) * 32];
    const bf16* vbase = Vt + base;

    for (int t = 0; t < 8; ++t) {
        const int s0 = t * 128;
        // K tile prefetch to regs (overlaps prev iter's PV)
        const bf16x8 kv0 = *(const bf16x8*)(kg + s0 * 64 + 0);
        const bf16x8 kv1 = *(const bf16x8*)(kg + s0 * 64 + 8);
        const bf16x8 kv2 = *(const bf16x8*)(kg + s0 * 64 + 16);
        const bf16x8 kv3 = *(const bf16x8*)(kg + s0 * 64 + 24);
        __syncthreads();
        *(bf16x8*)(kdst + 0) = kv0; *(bf16x8*)(kdst + 8) = kv1;
        *(bf16x8*)(kdst + 16) = kv2; *(bf16x8*)(kdst + 24) = kv3;
        __syncthreads();

        // QK^T joint over both q-halves: kf read once, used 4x
        f32x4 sf[2][8];
        __builtin_amdgcn_s_setprio(1);
#pragma unroll
        for (int j = 0; j < 8; ++j) {
            const bf16x8 kf0 = *(const bf16x8*)&Ksub[j * 16 + lrow][lk8];
            const bf16x8 kf1 = *(const bf16x8*)&Ksub[j * 16 + lrow][32 + lk8];
#pragma unroll
            for (int h = 0; h < 2; ++h) {
                f32x4 zz = f32x4{0.f, 0.f, 0.f, 0.f};
                zz = mfma16(qf[h][0], kf0, zz);
                sf[h][j] = mfma16(qf[h][1], kf1, zz);
            }
        }
        __builtin_amdgcn_s_setprio(0);

        // online softmax (base-2 domain; scale pre-folded into Q)
#pragma unroll
        for (int h = 0; h < 2; ++h) {
            float tmax[4];
#pragma unroll
            for (int r = 0; r < 4; ++r) tmax[r] = sf[h][0][r];
#pragma unroll
            for (int j = 1; j < 8; ++j)
#pragma unroll
                for (int r = 0; r < 4; ++r) tmax[r] = fmaxf(tmax[r], sf[h][j][r]);
#pragma unroll
            for (int r = 0; r < 4; ++r) {
                tmax[r] = fmaxf(tmax[r], __shfl_xor(tmax[r], 1));
                tmax[r] = fmaxf(tmax[r], __shfl_xor(tmax[r], 2));
                tmax[r] = fmaxf(tmax[r], __shfl_xor(tmax[r], 4));
                tmax[r] = fmaxf(tmax[r], __shfl_xor(tmax[r], 8));
            }
            float alpha[4];
#pragma unroll
            for (int r = 0; r < 4; ++r) {
                const float mn = fmaxf(m_r[h][r], tmax[r]);
                alpha[r] = __builtin_amdgcn_exp2f(m_r[h][r] - mn);
                m_r[h][r] = mn;
            }
            float tsum[4] = {0.f, 0.f, 0.f, 0.f};
#pragma unroll
            for (int j = 0; j < 8; ++j)
#pragma unroll
                for (int r = 0; r < 4; ++r) {
                    const float p = __builtin_amdgcn_exp2f(sf[h][j][r] - m_r[h][r]);
                    Psub[w][h * 16 + lr4 + r][j * 16 + lrow] = (bf16)p;
                    tsum[r] += p;
                }
#pragma unroll
            for (int r = 0; r < 4; ++r) {
                tsum[r] += __shfl_xor(tsum[r], 1);
                tsum[r] += __shfl_xor(tsum[r], 2);
                tsum[r] += __shfl_xor(tsum[r], 4);
                tsum[r] += __shfl_xor(tsum[r], 8);
                l_r[h][r] = l_r[h][r] * alpha[r] + tsum[r];
            }
#pragma unroll
            for (int n = 0; n < 4; ++n)
#pragma unroll
                for (int r = 0; r < 4; ++r) o[h][n][r] *= alpha[r];
        }

        // PV: O[32q x 64dh] += P[32 x 128] @ V[128 x 64]; V^T direct from global
        __builtin_amdgcn_s_setprio(1);
#pragma unroll
        for (int kk = 0; kk < 4; ++kk) {
            const bf16x8 pa0 = *(const bf16x8*)&Psub[w][lrow][kk * 32 + lk8];
            const bf16x8 pa1 = *(const bf16x8*)&Psub[w][16 + lrow][kk * 32 + lk8];
#pragma unroll
            for (int n = 0; n < 4; ++n) {
                const bf16x8 vf = *(const bf16x8*)(vbase +
                    (size_t)(n * 16 + lrow) * 1024 + s0 + kk * 32 + lk8);
                o[0][n] = mfma16(pa0, vf, o[0][n]);
                o[1][n] = mfma16(pa1, vf, o[1][n]);
            }
        }
        __builtin_amdgcn_s_setprio(0);
    }

    const int b = bh >> 4, hh = bh & 15;
#pragma unroll
    for (int h = 0; h < 2; ++h) {
        float inv[4];
#pragma unroll
        for (int r = 0; r < 4; ++r) inv[r] = 1.0f / l_r[h][r];
#pragma unroll
        for (int n = 0; n < 4; ++n)
#pragma unroll
            for (int r = 0; r < 4; ++r) {
                const int qrow = q0 + w * 32 + h * 16 + lr4 + r;
                out[((size_t)(b * 1024 + qrow)) * 1024 + hh * 64 + n * 16 + lrow] =
                    o[h][n][r] * inv[r];
            }
    }
}

extern "C" void kernel_launch(void* const* d_in, const int* in_sizes, int n_in,
                              void* d_out, int out_size, void* d_ws, size_t ws_size,
                              hipStream_t stream) {
    (void)in_sizes; (void)n_in; (void)out_size; (void)ws_size;
    const float* queries = (const float*)d_in[0];
    const float* keys    = (const float*)d_in[1];
    const float* values  = (const float*)d_in[2];
    const float* Wq      = (const float*)d_in[3];
    const float* Wk      = (const float*)d_in[4];
    const float* Wv      = (const float*)d_in[5];
    float* out = (float*)d_out;

    bf16* q_ws  = (bf16*)d_ws;
    bf16* k_ws  = q_ws + (size_t)8 * 1024 * 1024;
    bf16* vt_ws = k_ws + (size_t)8 * 1024 * 1024;
    bf16* wt_q  = vt_ws + (size_t)8 * 1024 * 1024;
    bf16* wt_k  = wt_q + (size_t)1024 * 1024;
    bf16* wt_v  = wt_k + (size_t)1024 * 1024;

    wconv_kernel<<<dim3(32, 32, 3), dim3(32, 8), 0, stream>>>(
        Wq, Wk, Wv, wt_q, wt_k, wt_v);
    gemm_proj<<<dim3(64, 8, 3), 256, 0, stream>>>(
        queries, keys, values, wt_q, wt_k, wt_v, q_ws, k_ws, vt_ws);
    attn_kernel<<<dim3(1024), 256, 0, stream>>>(q_ws, k_ws, vt_ws, out);
}